// Round 5
// baseline (168.559 us; speedup 1.0000x reference)
//
#include <hip/hip_runtime.h>

typedef __attribute__((ext_vector_type(8))) short short8;
typedef __attribute__((ext_vector_type(4))) float f32x4;

typedef __attribute__((address_space(3))) unsigned short lds_us;
typedef const __attribute__((address_space(1))) unsigned short glb_us;

__device__ __forceinline__ unsigned short f2bf(float x) {  // RNE (prep only)
  union { float f; unsigned u; } v; v.f = x;
  unsigned r = v.u + 0x7fffu + ((v.u >> 16) & 1u);
  return (unsigned short)(r >> 16);
}

// pack 2 f32 -> bf16x2 (a -> low half)
#if __has_builtin(__builtin_amdgcn_cvt_pk_bf16_f32)
__device__ __forceinline__ unsigned pk2(float a, float b) {
  return __builtin_bit_cast(unsigned, __builtin_amdgcn_cvt_pk_bf16_f32(a, b));
}
#else
__device__ __forceinline__ unsigned pk2(float a, float b) {
  union { float f; unsigned u; } x, y; x.f = a; y.f = b;
  return __builtin_amdgcn_perm(y.u + 0x8000u, x.u + 0x8000u, 0x07060302u);
}
#endif

// packed bf16 ReLU: int16 max vs 0 == fmax(.,0) on bf16 bits (validated R3).
__device__ __forceinline__ unsigned relu_pk(unsigned x) {
  unsigned r;
  asm("v_pk_max_i16 %0, %1, %2" : "=v"(r) : "v"(x), "v"(0));
  return r;
}

__device__ __forceinline__ short8 u2s8(uint4 u) {
  union { uint4 a; short8 b; } c; c.a = u; return c.b;
}

// compiler-level ordering within a wave (validated R5/R6 of prior session)
__device__ __forceinline__ void wave_mem_fence() {
  asm volatile("" ::: "memory");
  __builtin_amdgcn_wave_barrier();
  asm volatile("" ::: "memory");
}

// async copy: 64 lanes x 16B = 1 KB chunk, global -> LDS (width-16 variant)
__device__ __forceinline__ void gload16(const unsigned short* g, unsigned short* l) {
  __builtin_amdgcn_global_load_lds((glb_us*)g, (lds_us*)l, 16, 0, 0);
}

// acos(z)/pi, z clipped to [-1,1].
__device__ __forceinline__ float acos01(float z) {
  float ax = fminf(fabsf(z), 1.0f);
  float t  = __builtin_amdgcn_sqrtf(1.0f - ax);
  float p  = fmaf(ax, fmaf(ax, fmaf(ax, -0.00596110f, 0.02363618f),
                           -0.06751692f), 0.49998766f);
  p *= t;
  return z >= 0.0f ? p : 1.0f - p;
}

// atan2(y,x)/(2pi) + 0.5  in [0,1].
__device__ __forceinline__ float atan2_01(float y, float x) {
  float ax = fabsf(x), ay = fabsf(y);
  float hi = fmaxf(ax, ay), lo = fminf(ax, ay);
  float r  = lo * __builtin_amdgcn_rcpf(fmaxf(hi, 1e-30f));
  float r2 = r * r;
  float p  = fmaf(r2, fmaf(r2, fmaf(r2, fmaf(r2, fmaf(r2,
               -0.0018655370f, 0.0083800422f), -0.018531250f),
                0.030803547f), -0.052940457f), 0.159151323f);
  float q  = r * p;
  q = (ay > ax) ? 0.25f - q : q;
  q = (x < 0.0f) ? 0.5f - q : q;
  return 0.5f + ((y >= 0.0f) ? q : -q);
}

// gaussian one-blob, 4 bins -> two packed dwords
__device__ __forceinline__ uint2 blob4pk(float x) {
  float x4 = x * 4.0f;
  float e0, e1, e2, e3;
  { float t = x4 - 0.5f; e0 = __builtin_amdgcn_exp2f(t * t * -0.72134752f); }
  { float t = x4 - 1.5f; e1 = __builtin_amdgcn_exp2f(t * t * -0.72134752f); }
  { float t = x4 - 2.5f; e2 = __builtin_amdgcn_exp2f(t * t * -0.72134752f); }
  { float t = x4 - 3.5f; e3 = __builtin_amdgcn_exp2f(t * t * -0.72134752f); }
  return make_uint2(pk2(e0, e1), pk2(e2, e3));
}

// sin/cos of (2^i * pi * p), i=0..5: hardware sin+cos at base frequency,
// then exact double-angle recurrence (validated R3).
__device__ __forceinline__ void freq6(float p, float* s, float* c) {
  float fr = __builtin_amdgcn_fractf(0.5f * p);
  float sv = __builtin_amdgcn_sinf(fr);
  float cv = __builtin_amdgcn_cosf(fr);
  s[0] = sv; c[0] = cv;
#pragma unroll
  for (int i = 1; i < 6; ++i) {
    float t  = sv * cv;
    float ss = sv * sv;
    sv = t + t;
    cv = 1.0f - (ss + ss);
    s[i] = sv; c[i] = cv;
  }
}

// bf16 weights in d_ws, stored in WAVE-CONSUMPTION order (see R3 notes):
//   hidden: wb[l*4096 + ((t*2+h)*64 + lane)*8 + j]
//   W6:     wb[24576 + (h*64 + lane)*8 + j]   (rows >= 3 zero-padded)
__global__ void prep_weights(
    const float* __restrict__ W0, const float* __restrict__ W1,
    const float* __restrict__ W2, const float* __restrict__ W3,
    const float* __restrict__ W4, const float* __restrict__ W5,
    const float* __restrict__ W6, unsigned short* __restrict__ wb)
{
  int idx = blockIdx.x * blockDim.x + threadIdx.x;
  if (idx < 24576) {
    int l = idx >> 12;
    const float* W = (l==0)?W0:(l==1)?W1:(l==2)?W2:(l==3)?W3:(l==4)?W4:W5;
    int j   = idx & 7;
    int ln  = (idx >> 3) & 63;
    int h   = (idx >> 9) & 1;
    int t   = (idx >> 10) & 3;
    int n15 = ln & 15, q = ln >> 4;
    int src = 32*(t>>1) + 8*(n15>>2) + 4*(t&1) + (n15&3);
    int col = h*32 + q*8 + j;
    wb[idx] = f2bf(W[src*64 + col]);
  } else if (idx < 25600) {
    int i6  = idx - 24576;
    int j   = i6 & 7;
    int ln  = (i6 >> 3) & 63;
    int h   = (i6 >> 9) & 1;
    int n15 = ln & 15, q = ln >> 4;
    wb[idx] = (n15 < 3) ? f2bf(W6[n15*64 + h*32 + q*8 + j]) : (unsigned short)0;
  }
}

// 16 input floats for one row
struct Enc {
  float p0,p1,p2, wx,wy,wz, nx,ny,nz, a0,a1,a2, e0,e1,e2, rr;
};

__device__ __forceinline__ Enc load_inputs(
    const float* __restrict__ P, const float* __restrict__ WI,
    const float* __restrict__ NRM, const float* __restrict__ ALPHA,
    const float* __restrict__ BETA, const float* __restrict__ R, int row)
{
  Enc v;
  v.p0 = P[row*3+0];  v.p1 = P[row*3+1];  v.p2 = P[row*3+2];
  v.wx = WI[row*3+0]; v.wy = WI[row*3+1]; v.wz = WI[row*3+2];
  v.nx = NRM[row*3+0]; v.ny = NRM[row*3+1]; v.nz = NRM[row*3+2];
  v.a0 = ALPHA[row*3+0]; v.a1 = ALPHA[row*3+1]; v.a2 = ALPHA[row*3+2];
  v.e0 = BETA[row*3+0];  v.e1 = BETA[row*3+1];  v.e2 = BETA[row*3+2];
  v.rr = R[row];
  return v;
}

// Encode one 64-row tile, HALF-STAGED through a 4 KB per-wave X buffer:
// write cols 0-31 -> fence -> read b0 -> fence -> write cols 32-63 over the
// same slots -> fence -> read b1. Same-wave DS ops execute in issue order,
// so the overwrite is safe (structure validated R4; correctness passed).
// Layout: row stride 32 shorts (64 B = 4 granules); chunk c of row r lives
// at chunk (c ^ (r&3)).  Writes (lane=r, fixed c): granule (4r + c^(r&3))
// mod 32 -> each 8-lane group hits 8 distinct granules, 2 lanes/granule
// overall. Reads (row g*16+n15, chunk q^(n15&3)): granule (4*n15 + q^(n15&3))
// mod 32 -> 2 lanes/granule. Both conflict-free (same algebra family as the
// R2-validated XOR swizzle that measured SQ_LDS_BANK_CONFLICT=0).
__device__ __forceinline__ void encode_stage(
    const Enc& v, unsigned short* __restrict__ Xw,
    int lane, int n15, int q, uint4* b0, uint4* b1)
{
  unsigned short* xr = Xw + lane*32;
  const int sw  = lane & 3;
  const int swr = n15 & 3;
#define XST(c) (*(uint4*)(xr + (((c) ^ sw) << 3)))

  float s0[6], c0[6], s1[6], c1[6], s2[6], c2[6];
  freq6(v.p0, s0, c0);
  freq6(v.p1, s1, c1);
  freq6(v.p2, s2, c2);

  XST(0) = make_uint4(pk2(s0[0],s0[1]), pk2(s0[2],s0[3]),
                      pk2(s0[4],s0[5]), pk2(c0[0],c0[1]));
  XST(1) = make_uint4(pk2(c0[2],c0[3]), pk2(c0[4],c0[5]),
                      pk2(s1[0],s1[1]), pk2(s1[2],s1[3]));
  XST(2) = make_uint4(pk2(s1[4],s1[5]), pk2(c1[0],c1[1]),
                      pk2(c1[2],c1[3]), pk2(c1[4],c1[5]));
  XST(3) = make_uint4(pk2(s2[0],s2[1]), pk2(s2[2],s2[3]),
                      pk2(s2[4],s2[5]), pk2(c2[0],c2[1]));
  wave_mem_fence();
#pragma unroll
  for (int g = 0; g < 4; ++g)
    b0[g] = *(const uint4*)(Xw + (g*16 + n15)*32 + ((q ^ swr) << 3));
  wave_mem_fence();

  uint2 bwt = blob4pk(acos01(v.wz));
  uint2 bwp = blob4pk(atan2_01(v.wy, v.wx));
  uint2 bnt = blob4pk(acos01(v.nz));
  uint2 bnp = blob4pk(atan2_01(v.ny, v.nx));
  uint2 brr = blob4pk(1.0f - __builtin_amdgcn_exp2f(v.rr * -1.44269504f));

  XST(0) = make_uint4(pk2(c2[2],c2[3]), pk2(c2[4],c2[5]), bwt.x, bwt.y);
  XST(1) = make_uint4(bwp.x, bwp.y, bnt.x, bnt.y);
  XST(2) = make_uint4(bnp.x, bnp.y, brr.x, brr.y);
  XST(3) = make_uint4(pk2(v.a0,v.a1), pk2(v.a2,v.e0),
                      pk2(v.e1,v.e2), 0x3F803F80u);
  wave_mem_fence();
#pragma unroll
  for (int g = 0; g < 4; ++g)
    b1[g] = *(const uint4*)(Xw + (g*16 + n15)*32 + ((q ^ swr) << 3));
  wave_mem_fence();
#undef XST
}

// 64 rows/wave, 4 waves/block. Weights stream through a DOUBLE-buffered
// 2x8 KB LDS region via global_load_lds -> ONE barrier per layer; each
// layer issues its prefetch FIRST so the DMA has the whole MFMA phase to
// land. Hazard: gload into buf[(l+1)&1] overwrites data last READ in layer
// l-1; those ds_reads retired before the end-of-(l-1) barrier, and the
// gload is issued after it. Safe.
//
// LDS map (32768 B -> exactly 5 blocks/CU, 20 waves/CU):
//   shorts [   0,  8192) : W dbuf (buf b at b*4096)
//   shorts [8192, 16384) : X, 4 waves x 64 rows x 32-short stride
__global__ __launch_bounds__(256, 5) void nrc_mlp(
    const float* __restrict__ P, const float* __restrict__ WI,
    const float* __restrict__ NRM, const float* __restrict__ ALPHA,
    const float* __restrict__ BETA, const float* __restrict__ R,
    const unsigned short* __restrict__ wb, float* __restrict__ out)
{
  __shared__ __align__(16) unsigned short lds[16384];   // 32768 B
  const int lane = threadIdx.x & 63;
  const int wv   = threadIdx.x >> 6;
  const int n15  = lane & 15;
  const int q    = lane >> 4;
  const int l16  = lane * 8;                 // shorts: lane*16 bytes
  unsigned short* Xw = lds + 8192 + wv*2048;
  const int row0 = (blockIdx.x * 4 + wv) * 64;

  // inputs first (scalar loads retire without draining later gloads)
  Enc iv = load_inputs(P, WI, NRM, ALPHA, BETA, R, row0 + lane);

  // -------- issue W0 prefetch into buf0 (hidden under encode) --------
  {
    int c0 = 2*wv*512;               // this wave's two 1KB chunks
    gload16(wb + c0 + l16,        lds + c0 + l16);
    gload16(wb + c0 + 512 + l16,  lds + c0 + 512 + l16);
  }

  // -------- encode + B-fragments (half-staged, wave-private) --------
  uint4 b0[4], b1[4];
  encode_stage(iv, Xw, lane, n15, q, b0, b1);

  __syncthreads();    // drains W0 prefetch (vmcnt) for all waves

  const f32x4 z = {0.f, 0.f, 0.f, 0.f};

  // ---------- 6 hidden layers; W dbuf, ONE barrier per layer ----------
#pragma unroll
  for (int l = 0; l < 6; ++l) {
    // 1. prefetch next layer's weights (or W6) into the other buffer
    if (l < 5) {
      unsigned short* nb = lds + ((l+1) & 1) * 4096;
      int ns = (l+1) * 4096;
      int c0 = 2*wv*512;
      gload16(wb + ns + c0 + l16,       nb + c0 + l16);
      gload16(wb + ns + c0 + 512 + l16, nb + c0 + 512 + l16);
    } else if (wv < 2) {
      // W6 -> buf[(5+1)&1] = buf0
      int c0 = wv*512;
      gload16(wb + 24576 + c0 + l16, lds + c0 + l16);
    }

    // 2. this layer's A-fragments from buf[l&1]
    const unsigned short* Wl = lds + (l & 1) * 4096;
    short8 a0[4], a1[4];
#pragma unroll
    for (int k = 0; k < 4; ++k) {
      a0[k] = *(const short8*)(Wl + k*1024 + l16);
      a1[k] = *(const short8*)(Wl + k*1024 + 512 + l16);
    }

    // 3. 16 independent 2-deep MFMA chains (validated R3)
    f32x4 acc[4][4];   // [g][k], static indices only
#pragma unroll
    for (int k = 0; k < 4; ++k) {
#pragma unroll
      for (int g = 0; g < 4; ++g) {
        f32x4 c = __builtin_amdgcn_mfma_f32_16x16x32_bf16(a0[k], u2s8(b0[g]), z, 0, 0, 0);
        acc[g][k] = __builtin_amdgcn_mfma_f32_16x16x32_bf16(a1[k], u2s8(b1[g]), c, 0, 0, 0);
      }
    }

    // 4. repack + packed ReLU
#pragma unroll
    for (int g = 0; g < 4; ++g) {
      uint4 n0, n1;
      n0.x = relu_pk(pk2(acc[g][0][0], acc[g][0][1]));
      n0.y = relu_pk(pk2(acc[g][0][2], acc[g][0][3]));
      n0.z = relu_pk(pk2(acc[g][1][0], acc[g][1][1]));
      n0.w = relu_pk(pk2(acc[g][1][2], acc[g][1][3]));
      n1.x = relu_pk(pk2(acc[g][2][0], acc[g][2][1]));
      n1.y = relu_pk(pk2(acc[g][2][2], acc[g][2][3]));
      n1.z = relu_pk(pk2(acc[g][3][0], acc[g][3][1]));
      n1.w = relu_pk(pk2(acc[g][3][2], acc[g][3][3]));
      b0[g] = n0; b1[g] = n1;
    }
    __syncthreads();  // publishes next-layer weights (vmcnt drained)
  }

  // -------- output layer (W6 in buf0) + fused scale + direct store --------
  {
    short8 o0 = *(const short8*)(lds + l16);
    short8 o1 = *(const short8*)(lds + 512 + l16);
#pragma unroll
    for (int g = 0; g < 4; ++g) {
      f32x4 c = __builtin_amdgcn_mfma_f32_16x16x32_bf16(o0, u2s8(b0[g]), z, 0, 0, 0);
      c       = __builtin_amdgcn_mfma_f32_16x16x32_bf16(o1, u2s8(b1[g]), c, 0, 0, 0);
      if (q == 0) {
        int base = row0*3 + g*48 + n15*3;
        float3 av = *(const float3*)(ALPHA + base);
        float3 bv = *(const float3*)(BETA + base);
        float3 o;
        o.x = c[0] * (av.x + bv.x);
        o.y = c[1] * (av.y + bv.y);
        o.z = c[2] * (av.z + bv.z);
        *(float3*)(out + base) = o;
      }
    }
  }
}

extern "C" void kernel_launch(void* const* d_in, const int* in_sizes, int n_in,
                              void* d_out, int out_size, void* d_ws, size_t ws_size,
                              hipStream_t stream) {
  const float* P  = (const float*)d_in[0];
  const float* WI = (const float*)d_in[1];
  const float* NR = (const float*)d_in[2];
  const float* AL = (const float*)d_in[3];
  const float* BE = (const float*)d_in[4];
  const float* R  = (const float*)d_in[5];
  const float* W0 = (const float*)d_in[6];
  const float* W1 = (const float*)d_in[7];
  const float* W2 = (const float*)d_in[8];
  const float* W3 = (const float*)d_in[9];
  const float* W4 = (const float*)d_in[10];
  const float* W5 = (const float*)d_in[11];
  const float* W6 = (const float*)d_in[12];
  unsigned short* wb = (unsigned short*)d_ws;   // 25600 bf16 = 51200 B
  float* out = (float*)d_out;

  prep_weights<<<100, 256, 0, stream>>>(W0, W1, W2, W3, W4, W5, W6, wb);
  nrc_mlp<<<4096, 256, 0, stream>>>(P, WI, NR, AL, BE, R, wb, out);
}

// Round 6
// 164.195 us; speedup vs baseline: 1.0266x; 1.0266x over previous
//
#include <hip/hip_runtime.h>

typedef __attribute__((ext_vector_type(8))) short short8;
typedef __attribute__((ext_vector_type(4))) float f32x4;

typedef __attribute__((address_space(3))) unsigned short lds_us;
typedef const __attribute__((address_space(1))) unsigned short glb_us;

__device__ __forceinline__ unsigned short f2bf(float x) {  // RNE (prep only)
  union { float f; unsigned u; } v; v.f = x;
  unsigned r = v.u + 0x7fffu + ((v.u >> 16) & 1u);
  return (unsigned short)(r >> 16);
}

// pack 2 f32 -> bf16x2 (a -> low half)
#if __has_builtin(__builtin_amdgcn_cvt_pk_bf16_f32)
__device__ __forceinline__ unsigned pk2(float a, float b) {
  return __builtin_bit_cast(unsigned, __builtin_amdgcn_cvt_pk_bf16_f32(a, b));
}
#else
__device__ __forceinline__ unsigned pk2(float a, float b) {
  union { float f; unsigned u; } x, y; x.f = a; y.f = b;
  return __builtin_amdgcn_perm(y.u + 0x8000u, x.u + 0x8000u, 0x07060302u);
}
#endif

// packed bf16 ReLU: int16 max vs 0 == fmax(.,0) on bf16 bits (validated R3).
__device__ __forceinline__ unsigned relu_pk(unsigned x) {
  unsigned r;
  asm("v_pk_max_i16 %0, %1, %2" : "=v"(r) : "v"(x), "v"(0));
  return r;
}

__device__ __forceinline__ short8 u2s8(uint4 u) {
  union { uint4 a; short8 b; } c; c.a = u; return c.b;
}

// compiler-level ordering within a wave (validated)
__device__ __forceinline__ void wave_mem_fence() {
  asm volatile("" ::: "memory");
  __builtin_amdgcn_wave_barrier();
  asm volatile("" ::: "memory");
}

// async copy: 64 lanes x 16B = 1 KB chunk, global -> LDS (width-16 variant)
__device__ __forceinline__ void gload16(const unsigned short* g, unsigned short* l) {
  __builtin_amdgcn_global_load_lds((glb_us*)g, (lds_us*)l, 16, 0, 0);
}

// acos(z)/pi, z clipped to [-1,1].
__device__ __forceinline__ float acos01(float z) {
  float ax = fminf(fabsf(z), 1.0f);
  float t  = __builtin_amdgcn_sqrtf(1.0f - ax);
  float p  = fmaf(ax, fmaf(ax, fmaf(ax, -0.00596110f, 0.02363618f),
                           -0.06751692f), 0.49998766f);
  p *= t;
  return z >= 0.0f ? p : 1.0f - p;
}

// atan2(y,x)/(2pi) + 0.5  in [0,1].
__device__ __forceinline__ float atan2_01(float y, float x) {
  float ax = fabsf(x), ay = fabsf(y);
  float hi = fmaxf(ax, ay), lo = fminf(ax, ay);
  float r  = lo * __builtin_amdgcn_rcpf(fmaxf(hi, 1e-30f));
  float r2 = r * r;
  float p  = fmaf(r2, fmaf(r2, fmaf(r2, fmaf(r2, fmaf(r2,
               -0.0018655370f, 0.0083800422f), -0.018531250f),
                0.030803547f), -0.052940457f), 0.159151323f);
  float q  = r * p;
  q = (ay > ax) ? 0.25f - q : q;
  q = (x < 0.0f) ? 0.5f - q : q;
  return 0.5f + ((y >= 0.0f) ? q : -q);
}

// gaussian one-blob, 4 bins -> two packed dwords
__device__ __forceinline__ uint2 blob4pk(float x) {
  float x4 = x * 4.0f;
  float e0, e1, e2, e3;
  { float t = x4 - 0.5f; e0 = __builtin_amdgcn_exp2f(t * t * -0.72134752f); }
  { float t = x4 - 1.5f; e1 = __builtin_amdgcn_exp2f(t * t * -0.72134752f); }
  { float t = x4 - 2.5f; e2 = __builtin_amdgcn_exp2f(t * t * -0.72134752f); }
  { float t = x4 - 3.5f; e3 = __builtin_amdgcn_exp2f(t * t * -0.72134752f); }
  return make_uint2(pk2(e0, e1), pk2(e2, e3));
}

// sin/cos of (2^i * pi * p), i=0..5: hardware sin+cos at base frequency,
// then exact double-angle recurrence (validated R3).
__device__ __forceinline__ void freq6(float p, float* s, float* c) {
  float fr = __builtin_amdgcn_fractf(0.5f * p);
  float sv = __builtin_amdgcn_sinf(fr);
  float cv = __builtin_amdgcn_cosf(fr);
  s[0] = sv; c[0] = cv;
#pragma unroll
  for (int i = 1; i < 6; ++i) {
    float t  = sv * cv;
    float ss = sv * sv;
    sv = t + t;
    cv = 1.0f - (ss + ss);
    s[i] = sv; c[i] = cv;
  }
}

// bf16 weights in d_ws, stored in WAVE-CONSUMPTION order (see R3 notes):
//   hidden: wb[l*4096 + ((t*2+h)*64 + lane)*8 + j]
//   W6:     wb[24576 + (h*64 + lane)*8 + j]   (rows >= 3 zero-padded)
__global__ void prep_weights(
    const float* __restrict__ W0, const float* __restrict__ W1,
    const float* __restrict__ W2, const float* __restrict__ W3,
    const float* __restrict__ W4, const float* __restrict__ W5,
    const float* __restrict__ W6, unsigned short* __restrict__ wb)
{
  int idx = blockIdx.x * blockDim.x + threadIdx.x;
  if (idx < 24576) {
    int l = idx >> 12;
    const float* W = (l==0)?W0:(l==1)?W1:(l==2)?W2:(l==3)?W3:(l==4)?W4:W5;
    int j   = idx & 7;
    int ln  = (idx >> 3) & 63;
    int h   = (idx >> 9) & 1;
    int t   = (idx >> 10) & 3;
    int n15 = ln & 15, q = ln >> 4;
    int src = 32*(t>>1) + 8*(n15>>2) + 4*(t&1) + (n15&3);
    int col = h*32 + q*8 + j;
    wb[idx] = f2bf(W[src*64 + col]);
  } else if (idx < 25600) {
    int i6  = idx - 24576;
    int j   = i6 & 7;
    int ln  = (i6 >> 3) & 63;
    int h   = (i6 >> 9) & 1;
    int n15 = ln & 15, q = ln >> 4;
    wb[idx] = (n15 < 3) ? f2bf(W6[n15*64 + h*32 + q*8 + j]) : (unsigned short)0;
  }
}

// 64 rows/wave, 4 waves/block. R3 structure with DOUBLE-buffered weights:
// per layer {issue gload of W[l+1] into other buf -> ds_read a-frags from
// buf[l&1] -> 16 independent MFMA chains -> packed repack -> ONE barrier}.
// Barriers: 13 (R3) -> 7. The end-of-layer barrier both publishes buf[l+1]
// (compiler drains vmcnt before s_barrier) and retires all reads of
// buf[l&1] before it is overwritten at layer l+2's prefetch. W6 -> buf0
// during l=5 (l=5 reads buf1; no clash).
//
// LDS map (49152 B -> 3 blocks/CU), registers: __launch_bounds__(256,3)
// -> cap ~170 VGPR, no spill (R5's (256,5) spilled: WRITE_SIZE 4x).
//   shorts [    0,  8192) : W dbuf (buf b at b*4096)
//   shorts [ 8192, 24576) : X, 4 waves x 64 rows x 64 shorts
// X swizzle: chunk j of row r at chunk (j ^ (r&7)) — the ONLY pattern
// hardware-validated conflict-free (R2/R3: SQ_LDS_BANK_CONFLICT = 0).
__global__ __launch_bounds__(256, 3) void nrc_mlp(
    const float* __restrict__ P, const float* __restrict__ WI,
    const float* __restrict__ NRM, const float* __restrict__ ALPHA,
    const float* __restrict__ BETA, const float* __restrict__ R,
    const unsigned short* __restrict__ wb, float* __restrict__ out)
{
  __shared__ __align__(16) unsigned short lds[24576];   // 49152 B
  const int lane = threadIdx.x & 63;
  const int wv   = threadIdx.x >> 6;
  const int n15  = lane & 15;
  const int q    = lane >> 4;
  const int l16  = lane * 8;                 // shorts: lane*16 bytes
  unsigned short* Xw = lds + 8192 + (wv << 12);   // this wave's 64x64 X
  const int row0 = (blockIdx.x * 4 + wv) * 64;

  // -------- issue W0 prefetch into buf0 (hidden under encode) --------
  {
    int c0 = 2*wv*512;               // this wave's two 1KB chunks
    gload16(wb + c0 + l16,        lds + c0 + l16);
    gload16(wb + c0 + 512 + l16,  lds + c0 + 512 + l16);
  }

  // ---------------- encoding: lane <-> row (R3 verbatim) ----------------
  {
    const int row = row0 + lane;
    const int sw  = lane & 7;                    // row&7 for this lane's row
    unsigned short* xr = Xw + (lane << 6);
#define XST(j) (*(uint4*)(xr + (((j) ^ sw) << 3)))

    float s0[6], c0[6], s1[6], c1[6], s2[6], c2[6];
    freq6(P[row*3+0], s0, c0);
    freq6(P[row*3+1], s1, c1);
    freq6(P[row*3+2], s2, c2);

    XST(0) = make_uint4(pk2(s0[0],s0[1]), pk2(s0[2],s0[3]),
                        pk2(s0[4],s0[5]), pk2(c0[0],c0[1]));
    XST(1) = make_uint4(pk2(c0[2],c0[3]), pk2(c0[4],c0[5]),
                        pk2(s1[0],s1[1]), pk2(s1[2],s1[3]));
    XST(2) = make_uint4(pk2(s1[4],s1[5]), pk2(c1[0],c1[1]),
                        pk2(c1[2],c1[3]), pk2(c1[4],c1[5]));
    XST(3) = make_uint4(pk2(s2[0],s2[1]), pk2(s2[2],s2[3]),
                        pk2(s2[4],s2[5]), pk2(c2[0],c2[1]));

    uint2 bwt, bwp, bnt, bnp, brr;
    {
      float wx = WI[row*3+0], wy = WI[row*3+1], wz = WI[row*3+2];
      bwt = blob4pk(acos01(wz));
      bwp = blob4pk(atan2_01(wy, wx));
    }
    {
      float nx = NRM[row*3+0], ny = NRM[row*3+1], nz = NRM[row*3+2];
      bnt = blob4pk(acos01(nz));
      bnp = blob4pk(atan2_01(ny, nx));
    }
    brr = blob4pk(1.0f - __builtin_amdgcn_exp2f(R[row] * -1.44269504f));

    XST(4) = make_uint4(pk2(c2[2],c2[3]), pk2(c2[4],c2[5]), bwt.x, bwt.y);
    XST(5) = make_uint4(bwp.x, bwp.y, bnt.x, bnt.y);
    XST(6) = make_uint4(bnp.x, bnp.y, brr.x, brr.y);

    float a0 = ALPHA[row*3+0], a1 = ALPHA[row*3+1], a2 = ALPHA[row*3+2];
    float e0 = BETA[row*3+0],  e1 = BETA[row*3+1],  e2 = BETA[row*3+2];
    XST(7) = make_uint4(pk2(a0,a1), pk2(a2,e0), pk2(e1,e2), 0x3F803F80u);
#undef XST
  }
  wave_mem_fence();   // X writes -> X reads (same wave; DS in-order)

  // ---------------- initial B-fragments (4 groups of 16 rows) ----------
  uint4 b0[4], b1[4];
  {
    const int swr = n15 & 7;                 // (g*16+n15)&7 == n15&7
#pragma unroll
    for (int g = 0; g < 4; ++g) {
      const unsigned short* rb = Xw + ((g*16 + n15) << 6);
      b0[g] = *(const uint4*)(rb + (((q    ) ^ swr) << 3));
      b1[g] = *(const uint4*)(rb + (((q + 4) ^ swr) << 3));
    }
  }

  __syncthreads();    // drains W0 prefetch (vmcnt) for all waves

  const f32x4 z = {0.f, 0.f, 0.f, 0.f};

  // ---------- 6 hidden layers; W dbuf, ONE barrier per layer ----------
#pragma unroll
  for (int l = 0; l < 6; ++l) {
    // 1. prefetch next layer's weights (or W6) into the other buffer.
    //    Overwrites buf[l-1], whose reads retired before the l-1 barrier.
    if (l < 5) {
      unsigned short* nb = lds + ((l+1) & 1) * 4096;
      int ns = (l+1) * 4096;
      int c0 = 2*wv*512;
      gload16(wb + ns + c0 + l16,       nb + c0 + l16);
      gload16(wb + ns + c0 + 512 + l16, nb + c0 + 512 + l16);
    } else if (wv < 2) {
      int c0 = wv*512;
      gload16(wb + 24576 + c0 + l16, lds + c0 + l16);  // W6 -> buf0
    }

    // 2. this layer's A-fragments from buf[l&1]
    const unsigned short* Wl = lds + (l & 1) * 4096;
    short8 a0[4], a1[4];
#pragma unroll
    for (int k = 0; k < 4; ++k) {
      a0[k] = *(const short8*)(Wl + k*1024 + l16);
      a1[k] = *(const short8*)(Wl + k*1024 + 512 + l16);
    }

    // 3. 16 independent 2-deep MFMA chains (validated R3)
    f32x4 acc[4][4];   // [g][k], static indices only
#pragma unroll
    for (int k = 0; k < 4; ++k) {
#pragma unroll
      for (int g = 0; g < 4; ++g) {
        f32x4 c = __builtin_amdgcn_mfma_f32_16x16x32_bf16(a0[k], u2s8(b0[g]), z, 0, 0, 0);
        acc[g][k] = __builtin_amdgcn_mfma_f32_16x16x32_bf16(a1[k], u2s8(b1[g]), c, 0, 0, 0);
      }
    }

    // 4. repack + packed ReLU
#pragma unroll
    for (int g = 0; g < 4; ++g) {
      uint4 n0, n1;
      n0.x = relu_pk(pk2(acc[g][0][0], acc[g][0][1]));
      n0.y = relu_pk(pk2(acc[g][0][2], acc[g][0][3]));
      n0.z = relu_pk(pk2(acc[g][1][0], acc[g][1][1]));
      n0.w = relu_pk(pk2(acc[g][1][2], acc[g][1][3]));
      n1.x = relu_pk(pk2(acc[g][2][0], acc[g][2][1]));
      n1.y = relu_pk(pk2(acc[g][2][2], acc[g][2][3]));
      n1.z = relu_pk(pk2(acc[g][3][0], acc[g][3][1]));
      n1.w = relu_pk(pk2(acc[g][3][2], acc[g][3][3]));
      b0[g] = n0; b1[g] = n1;
    }
    __syncthreads();  // publishes buf[l+1] (vmcnt drained) + retires
                      // this layer's buf reads before l+2 overwrite
  }

  // -------- output layer (W6 in buf0) + fused scale + direct store --------
  {
    short8 o0 = *(const short8*)(lds + l16);
    short8 o1 = *(const short8*)(lds + 512 + l16);
#pragma unroll
    for (int g = 0; g < 4; ++g) {
      f32x4 c = __builtin_amdgcn_mfma_f32_16x16x32_bf16(o0, u2s8(b0[g]), z, 0, 0, 0);
      c       = __builtin_amdgcn_mfma_f32_16x16x32_bf16(o1, u2s8(b1[g]), c, 0, 0, 0);
      if (q == 0) {
        int base = row0*3 + g*48 + n15*3;
        float3 av = *(const float3*)(ALPHA + base);
        float3 bv = *(const float3*)(BETA + base);
        float3 o;
        o.x = c[0] * (av.x + bv.x);
        o.y = c[1] * (av.y + bv.y);
        o.z = c[2] * (av.z + bv.z);
        *(float3*)(out + base) = o;
      }
    }
  }
}

extern "C" void kernel_launch(void* const* d_in, const int* in_sizes, int n_in,
                              void* d_out, int out_size, void* d_ws, size_t ws_size,
                              hipStream_t stream) {
  const float* P  = (const float*)d_in[0];
  const float* WI = (const float*)d_in[1];
  const float* NR = (const float*)d_in[2];
  const float* AL = (const float*)d_in[3];
  const float* BE = (const float*)d_in[4];
  const float* R  = (const float*)d_in[5];
  const float* W0 = (const float*)d_in[6];
  const float* W1 = (const float*)d_in[7];
  const float* W2 = (const float*)d_in[8];
  const float* W3 = (const float*)d_in[9];
  const float* W4 = (const float*)d_in[10];
  const float* W5 = (const float*)d_in[11];
  const float* W6 = (const float*)d_in[12];
  unsigned short* wb = (unsigned short*)d_ws;   // 25600 bf16 = 51200 B
  float* out = (float*)d_out;

  prep_weights<<<100, 256, 0, stream>>>(W0, W1, W2, W3, W4, W5, W6, wb);
  nrc_mlp<<<4096, 256, 0, stream>>>(P, WI, NR, AL, BE, R, wb, out);
}

// Round 7
// 162.928 us; speedup vs baseline: 1.0346x; 1.0078x over previous
//
#include <hip/hip_runtime.h>

typedef __attribute__((ext_vector_type(8))) short short8;
typedef __attribute__((ext_vector_type(4))) float f32x4;

__device__ __forceinline__ unsigned short f2bf(float x) {  // RNE (prep only)
  union { float f; unsigned u; } v; v.f = x;
  unsigned r = v.u + 0x7fffu + ((v.u >> 16) & 1u);
  return (unsigned short)(r >> 16);
}

// pack 2 f32 -> bf16x2 (a -> low half)
#if __has_builtin(__builtin_amdgcn_cvt_pk_bf16_f32)
__device__ __forceinline__ unsigned pk2(float a, float b) {
  return __builtin_bit_cast(unsigned, __builtin_amdgcn_cvt_pk_bf16_f32(a, b));
}
#else
__device__ __forceinline__ unsigned pk2(float a, float b) {
  union { float f; unsigned u; } x, y; x.f = a; y.f = b;
  return __builtin_amdgcn_perm(y.u + 0x8000u, x.u + 0x8000u, 0x07060302u);
}
#endif

// packed bf16 ReLU: int16 max vs 0 == fmax(.,0) on bf16 bits (validated R3).
__device__ __forceinline__ unsigned relu_pk(unsigned x) {
  unsigned r;
  asm("v_pk_max_i16 %0, %1, %2" : "=v"(r) : "v"(x), "v"(0));
  return r;
}

__device__ __forceinline__ short8 u2s8(uint4 u) {
  union { uint4 a; short8 b; } c; c.a = u; return c.b;
}

// compiler-level ordering within a wave (validated)
__device__ __forceinline__ void wave_mem_fence() {
  asm volatile("" ::: "memory");
  __builtin_amdgcn_wave_barrier();
  asm volatile("" ::: "memory");
}

// acos(z)/pi, z clipped to [-1,1].
__device__ __forceinline__ float acos01(float z) {
  float ax = fminf(fabsf(z), 1.0f);
  float t  = __builtin_amdgcn_sqrtf(1.0f - ax);
  float p  = fmaf(ax, fmaf(ax, fmaf(ax, -0.00596110f, 0.02363618f),
                           -0.06751692f), 0.49998766f);
  p *= t;
  return z >= 0.0f ? p : 1.0f - p;
}

// atan2(y,x)/(2pi) + 0.5  in [0,1].
__device__ __forceinline__ float atan2_01(float y, float x) {
  float ax = fabsf(x), ay = fabsf(y);
  float hi = fmaxf(ax, ay), lo = fminf(ax, ay);
  float r  = lo * __builtin_amdgcn_rcpf(fmaxf(hi, 1e-30f));
  float r2 = r * r;
  float p  = fmaf(r2, fmaf(r2, fmaf(r2, fmaf(r2, fmaf(r2,
               -0.0018655370f, 0.0083800422f), -0.018531250f),
                0.030803547f), -0.052940457f), 0.159151323f);
  float q  = r * p;
  q = (ay > ax) ? 0.25f - q : q;
  q = (x < 0.0f) ? 0.5f - q : q;
  return 0.5f + ((y >= 0.0f) ? q : -q);
}

// gaussian one-blob, 4 bins -> two packed dwords
__device__ __forceinline__ uint2 blob4pk(float x) {
  float x4 = x * 4.0f;
  float e0, e1, e2, e3;
  { float t = x4 - 0.5f; e0 = __builtin_amdgcn_exp2f(t * t * -0.72134752f); }
  { float t = x4 - 1.5f; e1 = __builtin_amdgcn_exp2f(t * t * -0.72134752f); }
  { float t = x4 - 2.5f; e2 = __builtin_amdgcn_exp2f(t * t * -0.72134752f); }
  { float t = x4 - 3.5f; e3 = __builtin_amdgcn_exp2f(t * t * -0.72134752f); }
  return make_uint2(pk2(e0, e1), pk2(e2, e3));
}

// sin/cos of (2^i * pi * p), i=0..5: hardware sin+cos at base frequency,
// then exact double-angle recurrence (validated R3).
__device__ __forceinline__ void freq6(float p, float* s, float* c) {
  float fr = __builtin_amdgcn_fractf(0.5f * p);
  float sv = __builtin_amdgcn_sinf(fr);
  float cv = __builtin_amdgcn_cosf(fr);
  s[0] = sv; c[0] = cv;
#pragma unroll
  for (int i = 1; i < 6; ++i) {
    float t  = sv * cv;
    float ss = sv * sv;
    sv = t + t;
    cv = 1.0f - (ss + ss);
    s[i] = sv; c[i] = cv;
  }
}

// bf16 weights in d_ws, stored in WAVE-CONSUMPTION order (unchanged):
//   hidden: wb[l*4096 + ((t*2+h)*64 + lane)*8 + j]
//   W6:     wb[24576 + (h*64 + lane)*8 + j]   (rows >= 3 zero-padded)
// Lane reads a0[k] = wb[l*4096 + k*1024 + lane*8], a1[k] = +512 — each is a
// fully-coalesced 1KB wave read, permanently L1/L2-resident (50KB total).
__global__ void prep_weights(
    const float* __restrict__ W0, const float* __restrict__ W1,
    const float* __restrict__ W2, const float* __restrict__ W3,
    const float* __restrict__ W4, const float* __restrict__ W5,
    const float* __restrict__ W6, unsigned short* __restrict__ wb)
{
  int idx = blockIdx.x * blockDim.x + threadIdx.x;
  if (idx < 24576) {
    int l = idx >> 12;
    const float* W = (l==0)?W0:(l==1)?W1:(l==2)?W2:(l==3)?W3:(l==4)?W4:W5;
    int j   = idx & 7;
    int ln  = (idx >> 3) & 63;
    int h   = (idx >> 9) & 1;
    int t   = (idx >> 10) & 3;
    int n15 = ln & 15, q = ln >> 4;
    int src = 32*(t>>1) + 8*(n15>>2) + 4*(t&1) + (n15&3);
    int col = h*32 + q*8 + j;
    wb[idx] = f2bf(W[src*64 + col]);
  } else if (idx < 25600) {
    int i6  = idx - 24576;
    int j   = i6 & 7;
    int ln  = (i6 >> 3) & 63;
    int h   = (i6 >> 9) & 1;
    int n15 = ln & 15, q = ln >> 4;
    wb[idx] = (n15 < 3) ? f2bf(W6[n15*64 + h*32 + q*8 + j]) : (unsigned short)0;
  }
}

// 64 rows/wave, 4 waves/block. ZERO barriers: W A-fragments are loaded
// DIRECTLY from global (L1/L2-hot wb) into registers, double-buffered one
// layer ahead (aa[2][8], static parity indices under full unroll), so the
// ~200-300cy cache latency hides under the previous layer's MFMA+repack.
// LDS holds only the per-wave X staging (wave_mem_fence suffices; waves
// fully independent -> no convoy effects at all).
//
// LDS map (32768 B): X, 4 waves x 64 rows x 64 shorts.
// X swizzle: chunk j of row r at chunk (j ^ (r&7)) — the only pattern
// hardware-validated conflict-free (R2/R3/R6: SQ_LDS_BANK_CONFLICT = 0).
// Registers: __launch_bounds__(256,3) -> cap ~170; peak live ~160
// (aa 64 + b 32 + acc 64 partially overlapped). Spill tripwire: WRITE_SIZE.
__global__ __launch_bounds__(256, 3) void nrc_mlp(
    const float* __restrict__ P, const float* __restrict__ WI,
    const float* __restrict__ NRM, const float* __restrict__ ALPHA,
    const float* __restrict__ BETA, const float* __restrict__ R,
    const unsigned short* __restrict__ wb, float* __restrict__ out)
{
  __shared__ __align__(16) unsigned short lds[16384];   // 32768 B, X only
  const int lane = threadIdx.x & 63;
  const int wv   = threadIdx.x >> 6;
  const int n15  = lane & 15;
  const int q    = lane >> 4;
  const int l16  = lane * 8;                 // shorts: lane*16 bytes
  unsigned short* Xw = lds + (wv << 12);     // this wave's 64x64 X
  const int row0 = (blockIdx.x * 4 + wv) * 64;

  // -------- W0 A-fragments: issue global loads now, consumed after encode
  short8 aa[2][8];   // [parity][k<4 ? a0[k] : a1[k-4]]; static idx via unroll
#pragma unroll
  for (int k = 0; k < 4; ++k) {
    aa[0][k]   = *(const short8*)(wb + k*1024 + l16);
    aa[0][4+k] = *(const short8*)(wb + k*1024 + 512 + l16);
  }

  // ---------------- encoding: lane <-> row (R3 verbatim) ----------------
  {
    const int row = row0 + lane;
    const int sw  = lane & 7;                    // row&7 for this lane's row
    unsigned short* xr = Xw + (lane << 6);
#define XST(j) (*(uint4*)(xr + (((j) ^ sw) << 3)))

    float s0[6], c0[6], s1[6], c1[6], s2[6], c2[6];
    freq6(P[row*3+0], s0, c0);
    freq6(P[row*3+1], s1, c1);
    freq6(P[row*3+2], s2, c2);

    XST(0) = make_uint4(pk2(s0[0],s0[1]), pk2(s0[2],s0[3]),
                        pk2(s0[4],s0[5]), pk2(c0[0],c0[1]));
    XST(1) = make_uint4(pk2(c0[2],c0[3]), pk2(c0[4],c0[5]),
                        pk2(s1[0],s1[1]), pk2(s1[2],s1[3]));
    XST(2) = make_uint4(pk2(s1[4],s1[5]), pk2(c1[0],c1[1]),
                        pk2(c1[2],c1[3]), pk2(c1[4],c1[5]));
    XST(3) = make_uint4(pk2(s2[0],s2[1]), pk2(s2[2],s2[3]),
                        pk2(s2[4],s2[5]), pk2(c2[0],c2[1]));

    uint2 bwt, bwp, bnt, bnp, brr;
    {
      float wx = WI[row*3+0], wy = WI[row*3+1], wz = WI[row*3+2];
      bwt = blob4pk(acos01(wz));
      bwp = blob4pk(atan2_01(wy, wx));
    }
    {
      float nx = NRM[row*3+0], ny = NRM[row*3+1], nz = NRM[row*3+2];
      bnt = blob4pk(acos01(nz));
      bnp = blob4pk(atan2_01(ny, nx));
    }
    brr = blob4pk(1.0f - __builtin_amdgcn_exp2f(R[row] * -1.44269504f));

    XST(4) = make_uint4(pk2(c2[2],c2[3]), pk2(c2[4],c2[5]), bwt.x, bwt.y);
    XST(5) = make_uint4(bwp.x, bwp.y, bnt.x, bnt.y);
    XST(6) = make_uint4(bnp.x, bnp.y, brr.x, brr.y);

    float a0 = ALPHA[row*3+0], a1 = ALPHA[row*3+1], a2 = ALPHA[row*3+2];
    float e0 = BETA[row*3+0],  e1 = BETA[row*3+1],  e2 = BETA[row*3+2];
    XST(7) = make_uint4(pk2(a0,a1), pk2(a2,e0), pk2(e1,e2), 0x3F803F80u);
#undef XST
  }
  wave_mem_fence();   // X writes -> X reads (same wave; DS in-order)

  // ---------------- initial B-fragments (4 groups of 16 rows) ----------
  uint4 b0[4], b1[4];
  {
    const int swr = n15 & 7;                 // (g*16+n15)&7 == n15&7
#pragma unroll
    for (int g = 0; g < 4; ++g) {
      const unsigned short* rb = Xw + ((g*16 + n15) << 6);
      b0[g] = *(const uint4*)(rb + (((q    ) ^ swr) << 3));
      b1[g] = *(const uint4*)(rb + (((q + 4) ^ swr) << 3));
    }
  }

  const f32x4 z = {0.f, 0.f, 0.f, 0.f};

  // ---------- 6 hidden layers; W direct from cache, NO barriers ----------
#pragma unroll
  for (int l = 0; l < 6; ++l) {
    const int cur = l & 1, nxt = cur ^ 1;    // compile-time under unroll

    // prefetch next layer's A-fragments (or W6) into the other parity
    if (l < 5) {
      const unsigned short* wn = wb + (l+1)*4096 + l16;
#pragma unroll
      for (int k = 0; k < 4; ++k) {
        aa[nxt][k]   = *(const short8*)(wn + k*1024);
        aa[nxt][4+k] = *(const short8*)(wn + k*1024 + 512);
      }
    } else {
      aa[nxt][0] = *(const short8*)(wb + 24576 + l16);
      aa[nxt][1] = *(const short8*)(wb + 24576 + 512 + l16);
    }

    // 16 independent 2-deep MFMA chains (validated R3)
    f32x4 acc[4][4];   // [g][k], static indices only
#pragma unroll
    for (int k = 0; k < 4; ++k) {
#pragma unroll
      for (int g = 0; g < 4; ++g) {
        f32x4 c = __builtin_amdgcn_mfma_f32_16x16x32_bf16(aa[cur][k], u2s8(b0[g]), z, 0, 0, 0);
        acc[g][k] = __builtin_amdgcn_mfma_f32_16x16x32_bf16(aa[cur][4+k], u2s8(b1[g]), c, 0, 0, 0);
      }
    }

    // repack + packed ReLU
#pragma unroll
    for (int g = 0; g < 4; ++g) {
      uint4 n0, n1;
      n0.x = relu_pk(pk2(acc[g][0][0], acc[g][0][1]));
      n0.y = relu_pk(pk2(acc[g][0][2], acc[g][0][3]));
      n0.z = relu_pk(pk2(acc[g][1][0], acc[g][1][1]));
      n0.w = relu_pk(pk2(acc[g][1][2], acc[g][1][3]));
      n1.x = relu_pk(pk2(acc[g][2][0], acc[g][2][1]));
      n1.y = relu_pk(pk2(acc[g][2][2], acc[g][2][3]));
      n1.z = relu_pk(pk2(acc[g][3][0], acc[g][3][1]));
      n1.w = relu_pk(pk2(acc[g][3][2], acc[g][3][3]));
      b0[g] = n0; b1[g] = n1;
    }
  }

  // -------- output layer (W6 in aa[0][0..1]) + fused scale + store --------
  {
    short8 o0 = aa[0][0];
    short8 o1 = aa[0][1];
#pragma unroll
    for (int g = 0; g < 4; ++g) {
      f32x4 c = __builtin_amdgcn_mfma_f32_16x16x32_bf16(o0, u2s8(b0[g]), z, 0, 0, 0);
      c       = __builtin_amdgcn_mfma_f32_16x16x32_bf16(o1, u2s8(b1[g]), c, 0, 0, 0);
      if (q == 0) {
        int base = row0*3 + g*48 + n15*3;
        float3 av = *(const float3*)(ALPHA + base);
        float3 bv = *(const float3*)(BETA + base);
        float3 o;
        o.x = c[0] * (av.x + bv.x);
        o.y = c[1] * (av.y + bv.y);
        o.z = c[2] * (av.z + bv.z);
        *(float3*)(out + base) = o;
      }
    }
  }
}

extern "C" void kernel_launch(void* const* d_in, const int* in_sizes, int n_in,
                              void* d_out, int out_size, void* d_ws, size_t ws_size,
                              hipStream_t stream) {
  const float* P  = (const float*)d_in[0];
  const float* WI = (const float*)d_in[1];
  const float* NR = (const float*)d_in[2];
  const float* AL = (const float*)d_in[3];
  const float* BE = (const float*)d_in[4];
  const float* R  = (const float*)d_in[5];
  const float* W0 = (const float*)d_in[6];
  const float* W1 = (const float*)d_in[7];
  const float* W2 = (const float*)d_in[8];
  const float* W3 = (const float*)d_in[9];
  const float* W4 = (const float*)d_in[10];
  const float* W5 = (const float*)d_in[11];
  const float* W6 = (const float*)d_in[12];
  unsigned short* wb = (unsigned short*)d_ws;   // 25600 bf16 = 51200 B
  float* out = (float*)d_out;

  prep_weights<<<100, 256, 0, stream>>>(W0, W1, W2, W3, W4, W5, W6, wb);
  nrc_mlp<<<4096, 256, 0, stream>>>(P, WI, NR, AL, BE, R, wb, out);
}